// Round 19
// baseline (102.825 us; speedup 1.0000x reference)
//
#include <hip/hip_runtime.h>

#define B 256
#define N 2048
#define P 2048
#define C 10
#define S_CHUNKS 4
#define PPB (P / S_CHUNKS)     // 512 pairs per block
#define NIT (PPB / 32)         // 16 iterations; 32 pairs per block-iter
#define LN_EPS 1e-5f

typedef float v2f __attribute__((ext_vector_type(2)));
typedef _Float16 h2 __attribute__((ext_vector_type(2)));

// ---- f16 helpers (proven R11..R18) ------------------------------------------
static __device__ __forceinline__ float fdot2(h2 a, h2 b, float c) {
#if __has_builtin(__builtin_amdgcn_fdot2)
    return __builtin_amdgcn_fdot2(a, b, c, false);   // v_dot2_f32_f16
#else
    return (float)a.x * (float)b.x + (float)a.y * (float)b.y + c;
#endif
}
static __device__ __forceinline__ h2 h2fma(h2 a, h2 b, h2 c) {
#if __has_builtin(__builtin_elementwise_fma)
    return __builtin_elementwise_fma(a, b, c);        // v_pk_fma_f16
#else
    return a * b + c;
#endif
}
static __device__ __forceinline__ h2 h2relu(h2 x) {
#if __has_builtin(__builtin_elementwise_max)
    return __builtin_elementwise_max(x, h2{(_Float16)0.f, (_Float16)0.f});
#else
    h2 r;
    r.x = x.x > (_Float16)0.f ? x.x : (_Float16)0.f;
    r.y = x.y > (_Float16)0.f ? x.y : (_Float16)0.f;
    return r;
#endif
}
static __device__ __forceinline__ h2 pkrtz(float a, float b) {
#if __has_builtin(__builtin_amdgcn_cvt_pkrtz)
    return __builtin_bit_cast(h2, __builtin_amdgcn_cvt_pkrtz(a, b));
#else
    return h2{(_Float16)a, (_Float16)b};
#endif
}
static __device__ __forceinline__ unsigned pk_rne(float a, float b) {
    return __builtin_bit_cast(unsigned, h2{(_Float16)a, (_Float16)b});
}

// ---- 16-lane all-reduce sum via DPP butterfly (proven R2..R18) --------------
static __device__ __forceinline__ float red16(float x) {
    x += __int_as_float(__builtin_amdgcn_update_dpp(0, __float_as_int(x), 0xB1,  0xF, 0xF, true));
    x += __int_as_float(__builtin_amdgcn_update_dpp(0, __float_as_int(x), 0x4E,  0xF, 0xF, true));
    x += __int_as_float(__builtin_amdgcn_update_dpp(0, __float_as_int(x), 0x141, 0xF, 0xF, true));
    x += __int_as_float(__builtin_amdgcn_update_dpp(0, __float_as_int(x), 0x140, 0xF, 0xF, true));
    return x;
}

// ---------------------------------------------------------------------------
// Single fused kernel = R15 body (16-lane groups, 32.4 µs proven) + inline
// head on the last-arriving block per batch (cnt pre-zeroed each launch).
// ---------------------------------------------------------------------------
__global__ __launch_bounds__(256) void fused_kernel(
        const float* __restrict__ X,
        const float* __restrict__ W1, const float* __restrict__ b1,
        const float* __restrict__ gamma, const float* __restrict__ beta,
        const int*   __restrict__ pairs,
        const float* __restrict__ Wm1, const float* __restrict__ bm1,
        const float* __restrict__ Wm2, const float* __restrict__ bm2,
        const float* __restrict__ mem,
        float* __restrict__ part, int* __restrict__ cnt,
        float* __restrict__ out_logits, float* __restrict__ out_sdi) {
    const int b = blockIdx.x;
    const int chunk = blockIdx.y;
    const int tid = threadIdx.x;
    const int w = tid >> 6, l = tid & 63, g = l >> 4, s = l & 15;
    const int slot = w * 4 + g;      // 0..15

    __shared__ __align__(16) float lds[4096];  // 16 KB: T stage + reduce alias
    __shared__ float wf[4][128];                // folded weights; reused by head
    __shared__ float sc[9];
    __shared__ int lastFlag;
    uint2* Tl = (uint2*)lds;

    // ---- step 1: wave 0 computes the 9 scalars ----
    if (w == 0) {
        const float w0a = W1[l],       w0b = W1[l + 64];
        const float w1a = W1[128 + l], w1b = W1[128 + l + 64];
        const float bba = b1[l],       bbb = b1[l + 64];
        float s0 = w0a + w0b, s1 = w1a + w1b, sb = bba + bbb;
        #pragma unroll
        for (int m = 1; m < 64; m <<= 1) {
            s0 += __shfl_xor(s0, m);
            s1 += __shfl_xor(s1, m);
            sb += __shfl_xor(sb, m);
        }
        const float m0 = s0 * (1.f / 128.f);
        const float m1 = s1 * (1.f / 128.f);
        const float mb = sb * (1.f / 128.f);
        const float c0a = w0a - m0, c0b = w0b - m0;
        const float c1a = w1a - m1, c1b = w1b - m1;
        const float cba = bba - mb, cbb = bbb - mb;
        float q[6] = { c0a*c0a + c0b*c0b, c1a*c1a + c1b*c1b, cba*cba + cbb*cbb,
                       c0a*c1a + c0b*c1b, c0a*cba + c0b*cbb, c1a*cba + c1b*cbb };
        #pragma unroll
        for (int m = 1; m < 64; m <<= 1) {
            #pragma unroll
            for (int k = 0; k < 6; ++k) q[k] += __shfl_xor(q[k], m);
        }
        if (l < 6) sc[l] = q[l] * (1.f / 128.f);
        if (l == 6) sc[6] = m0;
        if (l == 7) sc[7] = m1;
        if (l == 8) sc[8] = mb;
    }
    __syncthreads();

    // ---- step 2a: weight arrays (f32) ----
    if (tid < 128) {
        const float m0 = sc[6], m1 = sc[7], mb = sc[8];
        const float g_ = gamma[tid];
        wf[0][tid] = g_ * (W1[tid] - m0);
        wf[1][tid] = g_ * (W1[128 + tid] - m1);
        wf[2][tid] = g_ * (b1[tid] - mb);
        wf[3][tid] = beta[tid];
    }

    // ---- step 2b: T slice for batch b, straight from X ----
    {
        const float S00 = sc[0], S11 = sc[1], Sbb = sc[2];
        const float S01 = sc[3], S0b = sc[4], S1b = sc[5];
        const float2* Xb = (const float2*)(X + (size_t)b * N * 2);
        #pragma unroll
        for (int q = 0; q < 8; ++q) {
            const int n = q * 256 + tid;
            const float2 x = Xb[n];
            const float v = fmaf(x.x * x.x, S00, fmaf(x.y * x.y, S11, Sbb))
                          + 2.f * fmaf(x.x * x.y, S01, fmaf(x.x, S0b, x.y * S1b));
            const float rs = rsqrtf(v + LN_EPS);
            Tl[n] = uint2{pk_rne(rs * x.x, rs * x.y), pk_rne(rs, 1.f)};
        }
    }
    __syncthreads();

    // ---- per-lane packed f16 weights: lane s owns (d, d+16), d = s+32m ----
    h2 gw0[4], gw1[4], gbc[4], be2[4];
    #pragma unroll
    for (int m = 0; m < 4; ++m) {
        const int d0 = s + 32 * m, d1 = d0 + 16;
        gw0[m] = h2{(_Float16)wf[0][d0], (_Float16)wf[0][d1]};
        gw1[m] = h2{(_Float16)wf[1][d0], (_Float16)wf[1][d1]};
        gbc[m] = h2{(_Float16)wf[2][d0], (_Float16)wf[2][d1]};
        be2[m] = h2{(_Float16)wf[3][d0], (_Float16)wf[3][d1]};
    }

    const int4* pr4 = (const int4*)pairs;      // 2 pairs per int4
    const int i4base = chunk * (PPB / 2);

    v2f acc[4];
    #pragma unroll
    for (int m = 0; m < 4; ++m) acc[m] = v2f{0.f, 0.f};

    auto proc = [&](const uint2 ti, const uint2 tj) {
        const h2 abi = __builtin_bit_cast(h2, ti.x), ci = __builtin_bit_cast(h2, ti.y);
        const h2 abj = __builtin_bit_cast(h2, tj.x), cj = __builtin_bit_cast(h2, tj.y);
        const h2 aai = h2{abi.x, abi.x}, bbi = h2{abi.y, abi.y}, cci = h2{ci.x, ci.x};
        const h2 aaj = h2{abj.x, abj.x}, bbj = h2{abj.y, abj.y}, ccj = h2{cj.x, cj.x};
        h2 uu[4], vv[4];
        float nu0 = 0.f, nu1 = 0.f, nv0 = 0.f, nv1 = 0.f;
        #pragma unroll
        for (int m = 0; m < 4; ++m) {
            const h2 hi = h2relu(h2fma(aai, gw0[m], h2fma(bbi, gw1[m], h2fma(cci, gbc[m], be2[m]))));
            const h2 hj = h2relu(h2fma(aaj, gw0[m], h2fma(bbj, gw1[m], h2fma(ccj, gbc[m], be2[m]))));
            const h2 u = hi - hj;
            const h2 v = hi + hj;
            if (m & 1) { nu1 = fdot2(u, u, nu1); nv1 = fdot2(v, v, nv1); }
            else       { nu0 = fdot2(u, u, nu0); nv0 = fdot2(v, v, nv0); }
            uu[m] = u; vv[m] = v;
        }
        const float nu = red16(nu0 + nu1);
        const float nv = red16(nv0 + nv1);
        const float ru = rsqrtf(fmaxf(nu, 1e-24f));
        const float rv = rsqrtf(fmaxf(nv, 1e-24f));
        const h2 ruv = pkrtz(ru, rv);
        #pragma unroll
        for (int m = 0; m < 4; ++m) {
            acc[m].x = fdot2(h2{uu[m].x, vv[m].x}, ruv, acc[m].x);
            acc[m].y = fdot2(h2{uu[m].y, vv[m].y}, ruv, acc[m].y);
        }
    };

    // ---- pipeline (R14/R15): idx 2 ahead, data 1 ahead ----
    const int4 idx0 = pr4[i4base + slot];
    int4 idxN = pr4[i4base + 16 + slot];
    uint2 tiA = Tl[idx0.x], tjA = Tl[idx0.y];
    uint2 tiB = Tl[idx0.z], tjB = Tl[idx0.w];

    for (int t = 0; t < NIT; ++t) {
        const uint2 ntiA = Tl[idxN.x], ntjA = Tl[idxN.y];
        const uint2 ntiB = Tl[idxN.z], ntjB = Tl[idxN.w];
        const int t2 = (t + 2 < NIT) ? (t + 2) : (NIT - 1);
        const int4 idxNN = pr4[i4base + t2 * 16 + slot];

        proc(tiA, tjA);
        proc(tiB, tjB);

        tiA = ntiA; tjA = ntjA; tiB = ntiB; tjB = ntjB;
        idxN = idxNN;
    }

    __syncthreads();                           // done reading staged T

    // reduce scratch aliases stage buffer: [slot][k][s] = lds[slot*136+k*17+s]
    #pragma unroll
    for (int m = 0; m < 4; ++m) {
        lds[slot * 136 + (2 * m)     * 17 + s] = acc[m].x;   // d = s + 32m
        lds[slot * 136 + (2 * m + 1) * 17 + s] = acc[m].y;   // d = s + 32m + 16
    }
    __syncthreads();
    if (tid < 128) {
        const int ss = tid & 15, kk = tid >> 4;   // d = ss + 16*kk == tid
        float sum = 0.f;
        #pragma unroll
        for (int q = 0; q < 16; ++q) sum += lds[q * 136 + kk * 17 + ss];
        part[((size_t)b * S_CHUNKS + chunk) * 128 + tid] = sum;
    }

    // ---- last block of batch b does the head (cnt pre-zeroed per launch) ----
    __threadfence();
    if (tid == 0) {
        const int old = atomicAdd(&cnt[b], 1);
        lastFlag = (old == S_CHUNKS - 1);
    }
    __syncthreads();
    if (!lastFlag) return;
    __threadfence();   // acquire: other blocks' part writes visible

    float* sA = wf[0];
    float* hA = wf[1];
    if (tid < 128) {
        float sv = 0.f;
        #pragma unroll
        for (int k = 0; k < S_CHUNKS; ++k)
            sv += part[((size_t)b * S_CHUNKS + k) * 128 + tid];
        sv *= (1.f / (2.f * P));
        sA[tid] = sv;
        out_sdi[(size_t)b * 128 + tid] = sv;
    }
    __syncthreads();
    if (tid < 128) {
        float a = bm1[tid];
        for (int d = 0; d < 128; ++d) a = fmaf(sA[d], Wm1[d * 128 + tid], a);
        hA[tid] = fmaxf(a, 0.f);
    }
    __syncthreads();
    if (tid < 16 * C) {
        const int c = tid >> 4, l16 = tid & 15;
        float lg = 0.f;
        #pragma unroll
        for (int q = 0; q < 8; ++q) {
            const int d = l16 + 16 * q;
            lg = fmaf(sA[d], mem[c * 128 + d], fmaf(hA[d], Wm2[d * C + c], lg));
        }
        lg = red16(lg);
        if (l16 == 0) out_logits[(size_t)b * C + c] = lg + bm2[c];
    }
}

extern "C" void kernel_launch(void* const* d_in, const int* in_sizes, int n_in,
                              void* d_out, int out_size, void* d_ws, size_t ws_size,
                              hipStream_t stream) {
    const float* X     = (const float*)d_in[0];
    const int*   pairs = (const int*)  d_in[1];
    const float* W1    = (const float*)d_in[2];
    const float* b1    = (const float*)d_in[3];
    const float* gamma = (const float*)d_in[4];
    const float* beta  = (const float*)d_in[5];
    const float* Wm1   = (const float*)d_in[6];
    const float* bm1   = (const float*)d_in[7];
    const float* Wm2   = (const float*)d_in[8];
    const float* bm2   = (const float*)d_in[9];
    const float* mem   = (const float*)d_in[10];

    float* out_logits = (float*)d_out;                 // B*C
    float* out_sdi    = (float*)d_out + (size_t)B * C; // B*128
    float* part = (float*)d_ws;                        // B*S_CHUNKS*128 floats
    int*   cnt  = (int*)((float*)d_ws + (size_t)B * S_CHUNKS * 128); // B ints

    // zero the arrival counters every call (stream-ordered, graph-capturable)
    hipMemsetAsync(cnt, 0, B * sizeof(int), stream);

    fused_kernel<<<dim3(B, S_CHUNKS), 256, 0, stream>>>(
        X, W1, b1, gamma, beta, pairs, Wm1, bm1, Wm2, bm2, mem,
        part, cnt, out_logits, out_sdi);
}

// Round 20
// 32.289 us; speedup vs baseline: 3.1845x; 3.1845x over previous
//
#include <hip/hip_runtime.h>

#define B 256
#define N 2048
#define P 2048
#define C 10
#define S_CHUNKS 4
#define PPB (P / S_CHUNKS)     // 512 pairs per block
#define NIT (PPB / 32)         // 16 iterations; 32 pairs per block-iter
#define LN_EPS 1e-5f

typedef float v2f __attribute__((ext_vector_type(2)));
typedef _Float16 h2 __attribute__((ext_vector_type(2)));

// ---- f16 helpers (proven R11..R15) ------------------------------------------
static __device__ __forceinline__ float fdot2(h2 a, h2 b, float c) {
#if __has_builtin(__builtin_amdgcn_fdot2)
    return __builtin_amdgcn_fdot2(a, b, c, false);   // v_dot2_f32_f16
#else
    return (float)a.x * (float)b.x + (float)a.y * (float)b.y + c;
#endif
}
static __device__ __forceinline__ h2 h2fma(h2 a, h2 b, h2 c) {
#if __has_builtin(__builtin_elementwise_fma)
    return __builtin_elementwise_fma(a, b, c);        // v_pk_fma_f16
#else
    return a * b + c;
#endif
}
static __device__ __forceinline__ h2 h2relu(h2 x) {
#if __has_builtin(__builtin_elementwise_max)
    return __builtin_elementwise_max(x, h2{(_Float16)0.f, (_Float16)0.f});
#else
    h2 r;
    r.x = x.x > (_Float16)0.f ? x.x : (_Float16)0.f;
    r.y = x.y > (_Float16)0.f ? x.y : (_Float16)0.f;
    return r;
#endif
}
static __device__ __forceinline__ h2 pkrtz(float a, float b) {
#if __has_builtin(__builtin_amdgcn_cvt_pkrtz)
    return __builtin_bit_cast(h2, __builtin_amdgcn_cvt_pkrtz(a, b));
#else
    return h2{(_Float16)a, (_Float16)b};
#endif
}
static __device__ __forceinline__ unsigned pk_rne(float a, float b) {
    return __builtin_bit_cast(unsigned, h2{(_Float16)a, (_Float16)b});
}

// ---- 16-lane all-reduce sum via DPP butterfly (proven R2..R15) --------------
static __device__ __forceinline__ float red16(float x) {
    x += __int_as_float(__builtin_amdgcn_update_dpp(0, __float_as_int(x), 0xB1,  0xF, 0xF, true));
    x += __int_as_float(__builtin_amdgcn_update_dpp(0, __float_as_int(x), 0x4E,  0xF, 0xF, true));
    x += __int_as_float(__builtin_amdgcn_update_dpp(0, __float_as_int(x), 0x141, 0xF, 0xF, true));
    x += __int_as_float(__builtin_amdgcn_update_dpp(0, __float_as_int(x), 0x140, 0xF, 0xF, true));
    return x;
}

// ---------------------------------------------------------------------------
// Fused kernel (R15, verbatim): per block (b, chunk):
//   1. wave 0 reduces means + 6 variance-quadratic scalars (shfl_xor)
//   2. build gamma-folded weights (LDS) + T slice for batch b (f16, LDS)
//   3. pair loop (16-lane groups, 2 pair-streams, idx 2 ahead, data 1 ahead)
//   4. block partial sdi -> global.
// ---------------------------------------------------------------------------
__global__ __launch_bounds__(256) void fused_kernel(
        const float* __restrict__ X,
        const float* __restrict__ W1, const float* __restrict__ b1,
        const float* __restrict__ gamma, const float* __restrict__ beta,
        const int*   __restrict__ pairs,
        float* __restrict__ part) {
    const int b = blockIdx.x;
    const int chunk = blockIdx.y;
    const int tid = threadIdx.x;
    const int w = tid >> 6, l = tid & 63, g = l >> 4, s = l & 15;
    const int slot = w * 4 + g;      // 0..15

    __shared__ __align__(16) float lds[4096];  // 16 KB: T stage + reduce alias
    __shared__ float wf[4][128];                // gamma-folded weights + beta
    __shared__ float sc[9];                     // S00,S11,Sbb,S01,S0b,S1b,m0,m1,mb
    uint2* Tl = (uint2*)lds;

    // ---- step 1: wave 0 computes the 9 scalars ----
    if (w == 0) {
        const float w0a = W1[l],       w0b = W1[l + 64];
        const float w1a = W1[128 + l], w1b = W1[128 + l + 64];
        const float bba = b1[l],       bbb = b1[l + 64];
        float s0 = w0a + w0b, s1 = w1a + w1b, sb = bba + bbb;
        #pragma unroll
        for (int m = 1; m < 64; m <<= 1) {
            s0 += __shfl_xor(s0, m);
            s1 += __shfl_xor(s1, m);
            sb += __shfl_xor(sb, m);
        }
        const float m0 = s0 * (1.f / 128.f);
        const float m1 = s1 * (1.f / 128.f);
        const float mb = sb * (1.f / 128.f);
        const float c0a = w0a - m0, c0b = w0b - m0;
        const float c1a = w1a - m1, c1b = w1b - m1;
        const float cba = bba - mb, cbb = bbb - mb;
        float q[6] = { c0a*c0a + c0b*c0b, c1a*c1a + c1b*c1b, cba*cba + cbb*cbb,
                       c0a*c1a + c0b*c1b, c0a*cba + c0b*cbb, c1a*cba + c1b*cbb };
        #pragma unroll
        for (int m = 1; m < 64; m <<= 1) {
            #pragma unroll
            for (int k = 0; k < 6; ++k) q[k] += __shfl_xor(q[k], m);
        }
        if (l < 6) sc[l] = q[l] * (1.f / 128.f);
        if (l == 6) sc[6] = m0;
        if (l == 7) sc[7] = m1;
        if (l == 8) sc[8] = mb;
    }
    __syncthreads();

    // ---- step 2a: weight arrays (f32) ----
    if (tid < 128) {
        const float m0 = sc[6], m1 = sc[7], mb = sc[8];
        const float g_ = gamma[tid];
        wf[0][tid] = g_ * (W1[tid] - m0);
        wf[1][tid] = g_ * (W1[128 + tid] - m1);
        wf[2][tid] = g_ * (b1[tid] - mb);
        wf[3][tid] = beta[tid];
    }

    // ---- step 2b: T slice for batch b, straight from X ----
    {
        const float S00 = sc[0], S11 = sc[1], Sbb = sc[2];
        const float S01 = sc[3], S0b = sc[4], S1b = sc[5];
        const float2* Xb = (const float2*)(X + (size_t)b * N * 2);
        #pragma unroll
        for (int q = 0; q < 8; ++q) {
            const int n = q * 256 + tid;
            const float2 x = Xb[n];
            const float v = fmaf(x.x * x.x, S00, fmaf(x.y * x.y, S11, Sbb))
                          + 2.f * fmaf(x.x * x.y, S01, fmaf(x.x, S0b, x.y * S1b));
            const float rs = rsqrtf(v + LN_EPS);
            Tl[n] = uint2{pk_rne(rs * x.x, rs * x.y), pk_rne(rs, 1.f)};
        }
    }
    __syncthreads();

    // ---- per-lane packed f16 weights from LDS ----
    h2 gw0[4], gw1[4], gbc[4], be2[4];
    #pragma unroll
    for (int m = 0; m < 4; ++m) {
        const int d0 = s + 32 * m, d1 = d0 + 16;
        gw0[m] = h2{(_Float16)wf[0][d0], (_Float16)wf[0][d1]};
        gw1[m] = h2{(_Float16)wf[1][d0], (_Float16)wf[1][d1]};
        gbc[m] = h2{(_Float16)wf[2][d0], (_Float16)wf[2][d1]};
        be2[m] = h2{(_Float16)wf[3][d0], (_Float16)wf[3][d1]};
    }

    const int4* pr4 = (const int4*)pairs;      // 2 pairs per int4
    const int i4base = chunk * (PPB / 2);

    v2f acc[4];
    #pragma unroll
    for (int m = 0; m < 4; ++m) acc[m] = v2f{0.f, 0.f};

    auto proc = [&](const uint2 ti, const uint2 tj) {
        const h2 abi = __builtin_bit_cast(h2, ti.x), ci = __builtin_bit_cast(h2, ti.y);
        const h2 abj = __builtin_bit_cast(h2, tj.x), cj = __builtin_bit_cast(h2, tj.y);
        const h2 aai = h2{abi.x, abi.x}, bbi = h2{abi.y, abi.y}, cci = h2{ci.x, ci.x};
        const h2 aaj = h2{abj.x, abj.x}, bbj = h2{abj.y, abj.y}, ccj = h2{cj.x, cj.x};
        h2 uu[4], vv[4];
        float nu0 = 0.f, nu1 = 0.f, nv0 = 0.f, nv1 = 0.f;
        #pragma unroll
        for (int m = 0; m < 4; ++m) {
            const h2 hi = h2relu(h2fma(aai, gw0[m], h2fma(bbi, gw1[m], h2fma(cci, gbc[m], be2[m]))));
            const h2 hj = h2relu(h2fma(aaj, gw0[m], h2fma(bbj, gw1[m], h2fma(ccj, gbc[m], be2[m]))));
            const h2 u = hi - hj;
            const h2 v = hi + hj;
            if (m & 1) { nu1 = fdot2(u, u, nu1); nv1 = fdot2(v, v, nv1); }
            else       { nu0 = fdot2(u, u, nu0); nv0 = fdot2(v, v, nv0); }
            uu[m] = u; vv[m] = v;
        }
        const float nu = red16(nu0 + nu1);
        const float nv = red16(nv0 + nv1);
        const float ru = rsqrtf(fmaxf(nu, 1e-24f));
        const float rv = rsqrtf(fmaxf(nv, 1e-24f));
        const h2 ruv = pkrtz(ru, rv);
        #pragma unroll
        for (int m = 0; m < 4; ++m) {
            acc[m].x = fdot2(h2{uu[m].x, vv[m].x}, ruv, acc[m].x);
            acc[m].y = fdot2(h2{uu[m].y, vv[m].y}, ruv, acc[m].y);
        }
    };

    // ---- pipeline prologue (R14 structure) ----
    const int4 idx0 = pr4[i4base + slot];
    int4 idxN = pr4[i4base + 16 + slot];
    uint2 tiA = Tl[idx0.x], tjA = Tl[idx0.y];
    uint2 tiB = Tl[idx0.z], tjB = Tl[idx0.w];

    for (int t = 0; t < NIT; ++t) {
        const uint2 ntiA = Tl[idxN.x], ntjA = Tl[idxN.y];
        const uint2 ntiB = Tl[idxN.z], ntjB = Tl[idxN.w];
        const int t2 = (t + 2 < NIT) ? (t + 2) : (NIT - 1);
        const int4 idxNN = pr4[i4base + t2 * 16 + slot];

        proc(tiA, tjA);
        proc(tiB, tjB);

        tiA = ntiA; tjA = ntjA; tiB = ntiB; tjB = ntjB;
        idxN = idxNN;
    }

    __syncthreads();                           // done reading staged T

    // reduce scratch aliases stage buffer: [slot][k][s] = lds[slot*136+k*17+s]
    #pragma unroll
    for (int m = 0; m < 4; ++m) {
        lds[slot * 136 + (2 * m)     * 17 + s] = acc[m].x;   // d = s + 32m
        lds[slot * 136 + (2 * m + 1) * 17 + s] = acc[m].y;   // d = s + 32m + 16
    }
    __syncthreads();
    if (tid < 128) {
        const int ss = tid & 15, kk = tid >> 4;   // d = ss + 16*kk == tid
        float sum = 0.f;
        #pragma unroll
        for (int q = 0; q < 16; ++q) sum += lds[q * 136 + kk * 17 + ss];
        part[((size_t)b * S_CHUNKS + chunk) * 128 + tid] = sum;
    }
}

// ---------------------------------------------------------------------------
// Kernel 2: reduce partials -> sdi, MLP head + mem logits.
// ---------------------------------------------------------------------------
__global__ __launch_bounds__(256) void head_kernel(
        const float* __restrict__ part,
        const float* __restrict__ Wm1, const float* __restrict__ bm1,
        const float* __restrict__ Wm2, const float* __restrict__ bm2,
        const float* __restrict__ mem,
        float* __restrict__ out_logits, float* __restrict__ out_sdi) {
    const int b = blockIdx.x;
    const int t = threadIdx.x;
    __shared__ float s[128];
    __shared__ float h[128];

    if (t < 128) {
        float sv = 0.f;
        #pragma unroll
        for (int k = 0; k < S_CHUNKS; ++k)
            sv += part[((size_t)b * S_CHUNKS + k) * 128 + t];
        sv *= (1.f / (2.f * P));
        s[t] = sv;
        out_sdi[(size_t)b * 128 + t] = sv;
    }
    __syncthreads();
    if (t < 128) {
        float a = bm1[t];
        for (int d = 0; d < 128; ++d) a = fmaf(s[d], Wm1[d * 128 + t], a);
        h[t] = fmaxf(a, 0.f);
    }
    __syncthreads();
    if (t < 16 * C) {                       // 160 threads: 16 lanes per class
        const int c = t >> 4, l = t & 15;
        float lg = 0.f;
        #pragma unroll
        for (int q = 0; q < 8; ++q) {
            const int d = l + 16 * q;
            lg = fmaf(s[d], mem[c * 128 + d], fmaf(h[d], Wm2[d * C + c], lg));
        }
        lg = red16(lg);
        if (l == 0) out_logits[(size_t)b * C + c] = lg + bm2[c];
    }
}

extern "C" void kernel_launch(void* const* d_in, const int* in_sizes, int n_in,
                              void* d_out, int out_size, void* d_ws, size_t ws_size,
                              hipStream_t stream) {
    const float* X     = (const float*)d_in[0];
    const int*   pairs = (const int*)  d_in[1];
    const float* W1    = (const float*)d_in[2];
    const float* b1    = (const float*)d_in[3];
    const float* gamma = (const float*)d_in[4];
    const float* beta  = (const float*)d_in[5];
    const float* Wm1   = (const float*)d_in[6];
    const float* bm1   = (const float*)d_in[7];
    const float* Wm2   = (const float*)d_in[8];
    const float* bm2   = (const float*)d_in[9];
    const float* mem   = (const float*)d_in[10];

    float* out = (float*)d_out;
    float* part = (float*)d_ws;                // B*S_CHUNKS*128 floats (512 KB)

    fused_kernel<<<dim3(B, S_CHUNKS), 256, 0, stream>>>(X, W1, b1, gamma, beta,
                                                        pairs, part);
    head_kernel<<<B, 256, 0, stream>>>(part, Wm1, bm1, Wm2, bm2, mem,
                                       out, out + (size_t)B * C);
}